// Round 24
// baseline (78.910 us; speedup 1.0000x reference)
//
#include <hip/hip_runtime.h>

// ---------- types & helpers ----------
typedef __attribute__((ext_vector_type(8))) short bf16x8;
typedef __attribute__((ext_vector_type(4))) float f32x4;
typedef __attribute__((ext_vector_type(4))) unsigned u32x4;

__device__ inline unsigned short f2bf(float f) {
  unsigned u = __builtin_bit_cast(unsigned, f);
  unsigned r = u + 0x7FFFu + ((u >> 16) & 1u);
  return (unsigned short)(r >> 16);
}
__device__ inline float bf2f(unsigned short s) {
  unsigned u = ((unsigned)s) << 16;
  return __builtin_bit_cast(float, u);
}
__device__ inline float fexp2(float x) { return __builtin_amdgcn_exp2f(x); }

__device__ inline void gload_lds16(const unsigned short* g, unsigned short* l) {
  __builtin_amdgcn_global_load_lds(
      (const __attribute__((address_space(1))) unsigned int*)g,
      (__attribute__((address_space(3))) unsigned int*)l, 16, 0, 0);
}

// PV key-permutation: key kappa (within 64-tile) -> slot k'
__device__ __host__ inline int pv_perm(int k) {
  return ((k >> 5) & 1) * 32 + ((k >> 2) & 3) * 8 + ((k >> 4) & 1) * 4 + (k & 3);
}

// ---------- fused preprocessing: x->bf16, 4 weight transposes, mask bias + tileok ----------
__global__ __launch_bounds__(256) void prep_kernel(
    const float* __restrict__ x, const int* __restrict__ mask,
    const float* __restrict__ w_q, const float* __restrict__ w_d,
    const float* __restrict__ w_k, const float* __restrict__ w_v,
    unsigned short* __restrict__ x_bf, unsigned short* __restrict__ wqdt,
    unsigned short* __restrict__ wkvt, float* __restrict__ bias,
    int* __restrict__ tileok) {
  int bid = blockIdx.x;
  if (bid < 1024) {  // x fp32 -> bf16
    int base = bid * 4096 + threadIdx.x * 4;
#pragma unroll
    for (int it = 0; it < 4; ++it) {
      int idx = base + it * 1024;
      float4 v = *(const float4*)&x[idx];
      ushort4 o;
      o.x = f2bf(v.x); o.y = f2bf(v.y); o.z = f2bf(v.z); o.w = f2bf(v.w);
      *(ushort4*)&x_bf[idx] = o;
    }
    return;
  }
  int tb = bid - 1024;
  if (tb >= 1408) {  // mask -> additive bias + per-64-key-tile all-valid flag
    int i = (tb - 1408) * 256 + threadIdx.x;
    int mv = mask[i];
    bias[i] = mv ? 0.0f : -1e30f;
    int ok = __all(mv != 0);
    if ((threadIdx.x & 63) == 0) tileok[i >> 6] = ok;
    return;
  }
  const float* in; unsigned short* out; int R, C, tr, tc;
  if (tb < 1024)      { in = w_q; out = wqdt;               R = 1024; C = 1024; tr = tb >> 5; tc = tb & 31; }
  else if (tb < 1152) { int t2 = tb - 1024; in = w_d; out = wqdt + 1024 * 1024; R = 1024; C = 128; tr = t2 >> 2; tc = t2 & 3; }
  else if (tb < 1280) { int t2 = tb - 1152; in = w_k; out = wkvt;               R = 128; C = 1024; tr = t2 >> 5; tc = t2 & 31; }
  else                { int t2 = tb - 1280; in = w_v; out = wkvt + 1024 * 128;  R = 128; C = 1024; tr = t2 >> 5; tc = t2 & 31; }
  __shared__ float t[32][33];
  int r0 = tr * 32, c0 = tc * 32;
  int tx = threadIdx.x & 31, ty = threadIdx.x >> 5;
  for (int r = ty; r < 32; r += 8)
    t[r][tx] = in[(size_t)(r0 + r) * C + c0 + tx];
  __syncthreads();
  for (int cc = ty; cc < 32; cc += 8)
    out[(size_t)(c0 + cc) * R + r0 + tx] = f2bf(t[tx][cc]);
}

// ---------- gemm1: qlat[4096][1152] = x_bf[4096][1024] * wqdt[1152][1024]^T ----------
__global__ __launch_bounds__(256) void gemm_q(const unsigned short* __restrict__ A,
                                              const unsigned short* __restrict__ Bt,
                                              unsigned short* __restrict__ C) {
  __shared__ unsigned short As[2][128 * 32];
  __shared__ unsigned short Bs[2][64 * 32];
  int m0 = blockIdx.x * 128, n0 = blockIdx.y * 64;
  int tid = threadIdx.x, w = tid >> 6, l = tid & 63;
  int lr = l & 15, lg = l >> 4;
  f32x4 acc[2][4] = {};

  for (int k0 = 0; k0 < 1024; k0 += 64) {
    __syncthreads();
#pragma unroll
    for (int it = 0; it < 4; ++it) {
      int s = w * 4 + it;
      int p = s >> 3, c = s & 7;
      int row = c * 16 + (l >> 2), col = (l & 3) * 8;
      gload_lds16(&A[(size_t)(m0 + row) * 1024 + k0 + p * 32 + col], &As[p][c * 512 + l * 8]);
    }
#pragma unroll
    for (int it = 0; it < 2; ++it) {
      int s = w * 2 + it;
      int p = s >> 2, c = s & 3;
      int row = c * 16 + (l >> 2), col = (l & 3) * 8;
      gload_lds16(&Bt[(size_t)(n0 + row) * 1024 + k0 + p * 32 + col], &Bs[p][c * 512 + l * 8]);
    }
    __syncthreads();
#pragma unroll
    for (int p = 0; p < 2; ++p) {
      bf16x8 af[2], bfr[4];
#pragma unroll
      for (int m = 0; m < 2; ++m)
        af[m] = *(const bf16x8*)&As[p][(w * 32 + m * 16 + lr) * 32 + lg * 8];
#pragma unroll
      for (int n = 0; n < 4; ++n)
        bfr[n] = *(const bf16x8*)&Bs[p][(n * 16 + lr) * 32 + lg * 8];
      __builtin_amdgcn_s_setprio(1);
#pragma unroll
      for (int m = 0; m < 2; ++m)
#pragma unroll
        for (int n = 0; n < 4; ++n)
          acc[m][n] = __builtin_amdgcn_mfma_f32_16x16x32_bf16(af[m], bfr[n], acc[m][n], 0, 0, 0);
      __builtin_amdgcn_s_setprio(0);
    }
  }

#pragma unroll
  for (int m = 0; m < 2; ++m)
#pragma unroll
    for (int n = 0; n < 4; ++n)
#pragma unroll
      for (int i = 0; i < 4; ++i)
        C[(size_t)(m0 + w * 32 + m * 16 + lg * 4 + i) * 1152 + n0 + n * 16 + lr] =
            f2bf(acc[m][n][i]);
}

// ---------- gemm2 (BK=64 dual-panel) with fused V transpose+permute epilogue ----------
__global__ __launch_bounds__(256) void gemm_kv(const unsigned short* __restrict__ A,
                                               const unsigned short* __restrict__ Bt,
                                               unsigned short* __restrict__ kvK,
                                               unsigned short* __restrict__ vt) {
  __shared__ unsigned short As[2][128 * 32];
  __shared__ unsigned short Bs[2][128 * 32];
  int m0 = blockIdx.x * 128, n0 = blockIdx.y * 128;
  int tid = threadIdx.x, w = tid >> 6, l = tid & 63;
  int lr = l & 15, lg = l >> 4;
  int wr = w >> 1, wc = w & 1;
  f32x4 acc[4][4] = {};

  for (int k0 = 0; k0 < 128; k0 += 64) {
    __syncthreads();
#pragma unroll
    for (int it = 0; it < 4; ++it) {
      int s = w * 4 + it;
      int p = s >> 3, c = s & 7;
      int row = c * 16 + (l >> 2), col = (l & 3) * 8;
      gload_lds16(&A[(size_t)(m0 + row) * 1152 + k0 + p * 32 + col], &As[p][c * 512 + l * 8]);
      gload_lds16(&Bt[(size_t)(n0 + row) * 128 + k0 + p * 32 + col], &Bs[p][c * 512 + l * 8]);
    }
    __syncthreads();
#pragma unroll
    for (int p = 0; p < 2; ++p) {
      bf16x8 af[4], bfr[4];
#pragma unroll
      for (int m = 0; m < 4; ++m)
        af[m] = *(const bf16x8*)&As[p][(wr * 64 + m * 16 + lr) * 32 + lg * 8];
#pragma unroll
      for (int n = 0; n < 4; ++n)
        bfr[n] = *(const bf16x8*)&Bs[p][(wc * 64 + n * 16 + lr) * 32 + lg * 8];
      __builtin_amdgcn_s_setprio(1);
#pragma unroll
      for (int m = 0; m < 4; ++m)
#pragma unroll
        for (int n = 0; n < 4; ++n)
          acc[m][n] = __builtin_amdgcn_mfma_f32_16x16x32_bf16(af[m], bfr[n], acc[m][n], 0, 0, 0);
      __builtin_amdgcn_s_setprio(0);
    }
  }

  if (blockIdx.y < 8) {  // K half
#pragma unroll
    for (int m = 0; m < 4; ++m)
#pragma unroll
      for (int n = 0; n < 4; ++n)
#pragma unroll
        for (int i = 0; i < 4; ++i)
          kvK[(size_t)(m0 + wr * 64 + m * 16 + lg * 4 + i) * 2048 + n0 + wc * 64 + n * 16 + lr] =
              f2bf(acc[m][n][i]);
  } else {  // V half: transposed + pv_perm'd
#pragma unroll
    for (int m = 0; m < 4; ++m)
#pragma unroll
      for (int n = 0; n < 4; ++n) {
        int vc = n0 - 1024 + wc * 64 + n * 16 + lr;
        int hh = vc >> 6, dd = vc & 63;
        int row0 = m0 + wr * 64 + m * 16 + lg * 4;
        int bb = row0 >> 11, t0 = row0 & 2047;
        size_t vrow = (size_t)((bb * 16 + hh) * 64 + dd);
        int slot = (t0 >> 6) * 64 + pv_perm(t0 & 63);
        ushort4 o;
        o.x = f2bf(acc[m][n][0]); o.y = f2bf(acc[m][n][1]);
        o.z = f2bf(acc[m][n][2]); o.w = f2bf(acc[m][n][3]);
        *(ushort4*)&vt[vrow * 2048 + slot] = o;
      }
  }
}

// ---------- flash attention: QBLK=128 (4 warps x 2 column-blocks), KVBLK=128 ----------
// grid (bh=32, y=16), band = 15 - y (heaviest first; 512 blocks = 2/CU).
// Warp w owns rows band*128 + qb*64 + w*16 + lr, qb=0,1. NT = band + 1.
// Single-buffered 35.8KB tile; K/V-frags loaded once, reused for both qb.
#define KSTR 72    // Ks row stride (64 d + 8 pad)
#define VSTR 136   // Vs row stride (128 keys + 8 pad)
__global__ __launch_bounds__(256, 2) void attn_kernel(const unsigned short* __restrict__ qg,
                                                      const unsigned short* __restrict__ kvg,
                                                      const unsigned short* __restrict__ vtg,
                                                      const float* __restrict__ biasg,
                                                      const int* __restrict__ tileokg,
                                                      float* __restrict__ outg) {
  const int bh = blockIdx.x, band = 15 - blockIdx.y;
  const int b = bh >> 4, h = bh & 15;
  const int tid = threadIdx.x, w = tid >> 6, l = tid & 63;
  const int lr = l & 15, lg = l >> 4;

  __shared__ unsigned short Ks[128 * KSTR];  // [key][d]
  __shared__ unsigned short Vs[64 * VSTR];   // [d][permuted key]

  const float QSCALE = 0.125f * 1.44269504089f;  // 1/sqrt(dh) * log2(e)

  const int NT = band + 1;                     // 128-key tiles for this band
  const int qrow0 = band * 128 + w * 16;       // qb adds +64
  // causal limit within diag tile for qb: keyl <= qb*64 + w*16 + lr

  // Q fragments, two column-blocks
  bf16x8 qf[2][2];
#pragma unroll
  for (int qb = 0; qb < 2; ++qb)
#pragma unroll
    for (int ks = 0; ks < 2; ++ks) {
      bf16x8 raw = *(const bf16x8*)&qg[(size_t)(b * 2048 + qrow0 + qb * 64 + lr) * 1152 +
                                       h * 64 + ks * 32 + lg * 8];
#pragma unroll
      for (int j = 0; j < 8; ++j)
        raw[j] = (short)f2bf(bf2f((unsigned short)raw[j]) * QSCALE);
      qf[qb][ks] = raw;
    }

  f32x4 acc[4][2] = {};            // [dt][qb]
  float m_i[2] = {-1e30f, -1e30f};
  float l_part[2] = {0.f, 0.f};

  // prologue: stage tile 0
  bf16x8 kreg[4], vreg[4];
#pragma unroll
  for (int it = 0; it < 4; ++it) {
    int slot = it * 256 + tid;
    int krow = slot >> 3, kc8 = (slot & 7) * 8;      // K: 128 rows x 8 chunks
    int vrow = slot >> 4, vc16 = (slot & 15) * 8;    // V: 64 rows x 16 chunks
    kreg[it] = *(const bf16x8*)&kvg[(size_t)(b * 2048 + krow) * 2048 + h * 64 + kc8];
    vreg[it] = *(const bf16x8*)&vtg[((size_t)(bh * 64 + vrow)) * 2048 + vc16];
  }
#pragma unroll
  for (int it = 0; it < 4; ++it) {
    int slot = it * 256 + tid;
    int krow = slot >> 3, kc8 = (slot & 7) * 8;
    int vrow = slot >> 4, vc16 = (slot & 15) * 8;
    *(bf16x8*)&Ks[krow * KSTR + kc8] = kreg[it];
    *(bf16x8*)&Vs[vrow * VSTR + vc16] = vreg[it];
  }
  __syncthreads();

  for (int kt = 0; kt < NT; ++kt) {
    // T14 async-stage: issue next tile's global loads now; LDS write after post-PV barrier
    if (kt + 1 < NT) {
#pragma unroll
      for (int it = 0; it < 4; ++it) {
        int slot = it * 256 + tid;
        int krow = slot >> 3, kc8 = (slot & 7) * 8;
        int vrow = slot >> 4, vc16 = (slot & 15) * 8;
        kreg[it] = *(const bf16x8*)&kvg[(size_t)(b * 2048 + (kt + 1) * 128 + krow) * 2048 + h * 64 + kc8];
        vreg[it] = *(const bf16x8*)&vtg[((size_t)(bh * 64 + vrow)) * 2048 + (kt + 1) * 128 + vc16];
      }
    }

    const bool diag = (kt == NT - 1);

    // S^T = K Q^T: 8 n-frags x 2 ks, K-frags reused for both qb
    f32x4 s[2][8];
    __builtin_amdgcn_s_setprio(1);
#pragma unroll
    for (int n = 0; n < 8; ++n) {
      bf16x8 kf0 = *(const bf16x8*)&Ks[(n * 16 + lr) * KSTR + lg * 8];
      bf16x8 kf1 = *(const bf16x8*)&Ks[(n * 16 + lr) * KSTR + 32 + lg * 8];
#pragma unroll
      for (int qb = 0; qb < 2; ++qb) {
        f32x4 z = {};
        z = __builtin_amdgcn_mfma_f32_16x16x32_bf16(kf0, qf[qb][0], z, 0, 0, 0);
        z = __builtin_amdgcn_mfma_f32_16x16x32_bf16(kf1, qf[qb][1], z, 0, 0, 0);
        s[qb][n] = z;
      }
    }
    __builtin_amdgcn_s_setprio(0);

    const int tok = tileokg[b * 32 + 2 * kt] & tileokg[b * 32 + 2 * kt + 1];
    float mx[2] = {-1e30f, -1e30f};
    if (tok) {
      if (diag) {
#pragma unroll
        for (int qb = 0; qb < 2; ++qb) {
          int dlim = qb * 64 + w * 16 + lr;
#pragma unroll
          for (int n = 0; n < 8; ++n)
#pragma unroll
            for (int i = 0; i < 4; ++i) {
              float v = (n * 16 + lg * 4 + i <= dlim) ? s[qb][n][i] : -1e30f;
              s[qb][n][i] = v;
              mx[qb] = fmaxf(mx[qb], v);
            }
        }
      } else {
#pragma unroll
        for (int qb = 0; qb < 2; ++qb)
#pragma unroll
          for (int n = 0; n < 8; ++n)
#pragma unroll
            for (int i = 0; i < 4; ++i)
              mx[qb] = fmaxf(mx[qb], s[qb][n][i]);
      }
    } else {  // rare general-mask path
#pragma unroll
      for (int n = 0; n < 8; ++n)
#pragma unroll
        for (int i = 0; i < 4; ++i) {
          int keyl = n * 16 + lg * 4 + i;
          float bsv = biasg[b * 2048 + kt * 128 + keyl];
#pragma unroll
          for (int qb = 0; qb < 2; ++qb) {
            float v = s[qb][n][i] + bsv;
            if (diag) v = (keyl <= qb * 64 + w * 16 + lr) ? v : -1e30f;
            s[qb][n][i] = v;
            mx[qb] = fmaxf(mx[qb], v);
          }
        }
    }
#pragma unroll
    for (int qb = 0; qb < 2; ++qb) {
      mx[qb] = fmaxf(mx[qb], __shfl_xor(mx[qb], 16, 64));
      mx[qb] = fmaxf(mx[qb], __shfl_xor(mx[qb], 32, 64));
    }

    // T13 defer-rescale (THR=8 in log2 domain), both qb checked together
    float g = fmaxf(mx[0] - m_i[0], mx[1] - m_i[1]);
    if (__any(g > 8.0f)) {
#pragma unroll
      for (int qb = 0; qb < 2; ++qb) {
        float mn = fmaxf(m_i[qb], mx[qb]);
        float sc = fexp2(m_i[qb] - mn);
        m_i[qb] = mn;
        l_part[qb] *= sc;
        float scb[4];
#pragma unroll
        for (int i = 0; i < 4; ++i) scb[i] = __shfl(sc, lg * 4 + i, 64);
#pragma unroll
        for (int dt = 0; dt < 4; ++dt)
#pragma unroll
          for (int i = 0; i < 4; ++i) acc[dt][qb][i] *= scb[i];
      }
    }

#pragma unroll
    for (int qb = 0; qb < 2; ++qb) {
      float rs = 0.f;
#pragma unroll
      for (int n = 0; n < 8; ++n)
#pragma unroll
        for (int i = 0; i < 4; ++i) {
          float e = fexp2(s[qb][n][i] - m_i[qb]);
          s[qb][n][i] = e;
          rs += e;
        }
      l_part[qb] += rs;
    }

    // P -> PV A-fragments in registers (V pre-permuted by pv_perm per 64-sub-tile)
    bf16x8 paf[2][4];
#pragma unroll
    for (int qb = 0; qb < 2; ++qb)
#pragma unroll
      for (int ks = 0; ks < 4; ++ks) {
        unsigned t0, t1, t2, t3;
        asm("v_cvt_pk_bf16_f32 %0, %1, %2" : "=v"(t0) : "v"(s[qb][2 * ks][0]), "v"(s[qb][2 * ks][1]));
        asm("v_cvt_pk_bf16_f32 %0, %1, %2" : "=v"(t1) : "v"(s[qb][2 * ks][2]), "v"(s[qb][2 * ks][3]));
        asm("v_cvt_pk_bf16_f32 %0, %1, %2" : "=v"(t2) : "v"(s[qb][2 * ks + 1][0]), "v"(s[qb][2 * ks + 1][1]));
        asm("v_cvt_pk_bf16_f32 %0, %1, %2" : "=v"(t3) : "v"(s[qb][2 * ks + 1][2]), "v"(s[qb][2 * ks + 1][3]));
        u32x4 uv;
        uv[0] = t0; uv[1] = t1; uv[2] = t2; uv[3] = t3;
        paf[qb][ks] = __builtin_bit_cast(bf16x8, uv);
      }

    // O += P V: V-frag loaded once per (ks,dt), reused for both qb
    __builtin_amdgcn_s_setprio(1);
#pragma unroll
    for (int ks = 0; ks < 4; ++ks)
#pragma unroll
      for (int dt = 0; dt < 4; ++dt) {
        bf16x8 vf = *(const bf16x8*)&Vs[(dt * 16 + lr) * VSTR + ks * 32 + lg * 8];
#pragma unroll
        for (int qb = 0; qb < 2; ++qb)
          acc[dt][qb] = __builtin_amdgcn_mfma_f32_16x16x32_bf16(paf[qb][ks], vf, acc[dt][qb], 0, 0, 0);
      }
    __builtin_amdgcn_s_setprio(0);

    // single-buffer swap: all reads done -> overwrite -> writes visible
    if (kt + 1 < NT) {
      __syncthreads();
#pragma unroll
      for (int it = 0; it < 4; ++it) {
        int slot = it * 256 + tid;
        int krow = slot >> 3, kc8 = (slot & 7) * 8;
        int vrow = slot >> 4, vc16 = (slot & 15) * 8;
        *(bf16x8*)&Ks[krow * KSTR + kc8] = kreg[it];
        *(bf16x8*)&Vs[vrow * VSTR + vc16] = vreg[it];
      }
      __syncthreads();
    }
  }

  // epilogue: finish l reduction, normalize, store both column-blocks
#pragma unroll
  for (int qb = 0; qb < 2; ++qb) {
    float lt = l_part[qb];
    lt += __shfl_xor(lt, 16, 64);
    lt += __shfl_xor(lt, 32, 64);
    float inv = 1.f / lt;
    float invb[4];
#pragma unroll
    for (int i = 0; i < 4; ++i) invb[i] = __shfl(inv, lg * 4 + i, 64);
#pragma unroll
    for (int dt = 0; dt < 4; ++dt)
#pragma unroll
      for (int i = 0; i < 4; ++i)
        outg[(size_t)(b * 2048 + qrow0 + qb * 64 + lg * 4 + i) * 1024 + h * 64 + dt * 16 + lr] =
            acc[dt][qb][i] * invb[i];
  }
}

// ---------- launch ----------
extern "C" void kernel_launch(void* const* d_in, const int* in_sizes, int n_in,
                              void* d_out, int out_size, void* d_ws, size_t ws_size,
                              hipStream_t stream) {
  const float* x    = (const float*)d_in[0];
  const int*   mask = (const int*)d_in[1];
  const float* w_q  = (const float*)d_in[2];
  const float* w_d  = (const float*)d_in[3];
  const float* w_k  = (const float*)d_in[4];
  const float* w_v  = (const float*)d_in[5];
  float* out = (float*)d_out;

  char* ws = (char*)d_ws;
  size_t off = 0;
  auto alloc = [&](size_t elems) {
    unsigned short* p = (unsigned short*)(ws + off);
    off += ((elems * 2 + 255) & ~(size_t)255);
    return p;
  };
  unsigned short* x_bf = alloc(4194304);      // [4096][1024]
  unsigned short* wqdt = alloc(1152 * 1024);  // [1152][1024]
  unsigned short* wkvt = alloc(2048 * 128);   // [2048][128]
  unsigned short* qlat = alloc(4096 * 1152);  // [4096][1152]: q | latent
  unsigned short* kv   = alloc(4096 * 2048);  // [4096][2048]: K in cols 0..1023
  unsigned short* vt   = alloc(4194304);      // [32][64][2048], pv_perm'd
  float* bias = (float*)alloc(8192);          // 4096 floats
  int* tileok = (int*)alloc(128);             // 64 ints

  prep_kernel<<<2448, 256, 0, stream>>>(x, mask, w_q, w_d, w_k, w_v, x_bf, wqdt, wkvt, bias, tileok);

  gemm_q<<<dim3(32, 18), 256, 0, stream>>>(x_bf, wqdt, qlat);
  gemm_kv<<<dim3(32, 16), 256, 0, stream>>>(qlat + 1024, wkvt, kv, vt);

  attn_kernel<<<dim3(32, 16), 256, 0, stream>>>(qlat, kv, vt, bias, tileok, out);
}

// Round 25
// 72.860 us; speedup vs baseline: 1.0830x; 1.0830x over previous
//
#include <hip/hip_runtime.h>

// ---------- types & helpers ----------
typedef __attribute__((ext_vector_type(8))) short bf16x8;
typedef __attribute__((ext_vector_type(4))) float f32x4;
typedef __attribute__((ext_vector_type(4))) unsigned u32x4;

__device__ inline unsigned short f2bf(float f) {
  unsigned u = __builtin_bit_cast(unsigned, f);
  unsigned r = u + 0x7FFFu + ((u >> 16) & 1u);
  return (unsigned short)(r >> 16);
}
__device__ inline float bf2f(unsigned short s) {
  unsigned u = ((unsigned)s) << 16;
  return __builtin_bit_cast(float, u);
}
__device__ inline float fexp2(float x) { return __builtin_amdgcn_exp2f(x); }

__device__ inline void gload_lds16(const unsigned short* g, unsigned short* l) {
  __builtin_amdgcn_global_load_lds(
      (const __attribute__((address_space(1))) unsigned int*)g,
      (__attribute__((address_space(3))) unsigned int*)l, 16, 0, 0);
}

// PV key-permutation: key kappa (within 64-tile) -> slot k'
__device__ __host__ inline int pv_perm(int k) {
  return ((k >> 5) & 1) * 32 + ((k >> 2) & 3) * 8 + ((k >> 4) & 1) * 4 + (k & 3);
}

// ---------- fused preprocessing: x->bf16, 4 weight transposes, mask bias + tileok ----------
__global__ __launch_bounds__(256) void prep_kernel(
    const float* __restrict__ x, const int* __restrict__ mask,
    const float* __restrict__ w_q, const float* __restrict__ w_d,
    const float* __restrict__ w_k, const float* __restrict__ w_v,
    unsigned short* __restrict__ x_bf, unsigned short* __restrict__ wqdt,
    unsigned short* __restrict__ wkvt, float* __restrict__ bias,
    int* __restrict__ tileok) {
  int bid = blockIdx.x;
  if (bid < 1024) {  // x fp32 -> bf16
    int base = bid * 4096 + threadIdx.x * 4;
#pragma unroll
    for (int it = 0; it < 4; ++it) {
      int idx = base + it * 1024;
      float4 v = *(const float4*)&x[idx];
      ushort4 o;
      o.x = f2bf(v.x); o.y = f2bf(v.y); o.z = f2bf(v.z); o.w = f2bf(v.w);
      *(ushort4*)&x_bf[idx] = o;
    }
    return;
  }
  int tb = bid - 1024;
  if (tb >= 1408) {  // mask -> additive bias + per-64-key-tile all-valid flag
    int i = (tb - 1408) * 256 + threadIdx.x;
    int mv = mask[i];
    bias[i] = mv ? 0.0f : -1e30f;
    int ok = __all(mv != 0);
    if ((threadIdx.x & 63) == 0) tileok[i >> 6] = ok;
    return;
  }
  const float* in; unsigned short* out; int R, C, tr, tc;
  if (tb < 1024)      { in = w_q; out = wqdt;               R = 1024; C = 1024; tr = tb >> 5; tc = tb & 31; }
  else if (tb < 1152) { int t2 = tb - 1024; in = w_d; out = wqdt + 1024 * 1024; R = 1024; C = 128; tr = t2 >> 2; tc = t2 & 3; }
  else if (tb < 1280) { int t2 = tb - 1152; in = w_k; out = wkvt;               R = 128; C = 1024; tr = t2 >> 5; tc = t2 & 31; }
  else                { int t2 = tb - 1280; in = w_v; out = wkvt + 1024 * 128;  R = 128; C = 1024; tr = t2 >> 5; tc = t2 & 31; }
  __shared__ float t[32][33];
  int r0 = tr * 32, c0 = tc * 32;
  int tx = threadIdx.x & 31, ty = threadIdx.x >> 5;
  for (int r = ty; r < 32; r += 8)
    t[r][tx] = in[(size_t)(r0 + r) * C + c0 + tx];
  __syncthreads();
  for (int cc = ty; cc < 32; cc += 8)
    out[(size_t)(c0 + cc) * R + r0 + tx] = f2bf(t[tx][cc]);
}

// ---------- gemm1: qlat[4096][1152] = x_bf[4096][1024] * wqdt[1152][1024]^T ----------
__global__ __launch_bounds__(256) void gemm_q(const unsigned short* __restrict__ A,
                                              const unsigned short* __restrict__ Bt,
                                              unsigned short* __restrict__ C) {
  __shared__ unsigned short As[2][128 * 32];
  __shared__ unsigned short Bs[2][64 * 32];
  int m0 = blockIdx.x * 128, n0 = blockIdx.y * 64;
  int tid = threadIdx.x, w = tid >> 6, l = tid & 63;
  int lr = l & 15, lg = l >> 4;
  f32x4 acc[2][4] = {};

  for (int k0 = 0; k0 < 1024; k0 += 64) {
    __syncthreads();
#pragma unroll
    for (int it = 0; it < 4; ++it) {
      int s = w * 4 + it;
      int p = s >> 3, c = s & 7;
      int row = c * 16 + (l >> 2), col = (l & 3) * 8;
      gload_lds16(&A[(size_t)(m0 + row) * 1024 + k0 + p * 32 + col], &As[p][c * 512 + l * 8]);
    }
#pragma unroll
    for (int it = 0; it < 2; ++it) {
      int s = w * 2 + it;
      int p = s >> 2, c = s & 3;
      int row = c * 16 + (l >> 2), col = (l & 3) * 8;
      gload_lds16(&Bt[(size_t)(n0 + row) * 1024 + k0 + p * 32 + col], &Bs[p][c * 512 + l * 8]);
    }
    __syncthreads();
#pragma unroll
    for (int p = 0; p < 2; ++p) {
      bf16x8 af[2], bfr[4];
#pragma unroll
      for (int m = 0; m < 2; ++m)
        af[m] = *(const bf16x8*)&As[p][(w * 32 + m * 16 + lr) * 32 + lg * 8];
#pragma unroll
      for (int n = 0; n < 4; ++n)
        bfr[n] = *(const bf16x8*)&Bs[p][(n * 16 + lr) * 32 + lg * 8];
      __builtin_amdgcn_s_setprio(1);
#pragma unroll
      for (int m = 0; m < 2; ++m)
#pragma unroll
        for (int n = 0; n < 4; ++n)
          acc[m][n] = __builtin_amdgcn_mfma_f32_16x16x32_bf16(af[m], bfr[n], acc[m][n], 0, 0, 0);
      __builtin_amdgcn_s_setprio(0);
    }
  }

#pragma unroll
  for (int m = 0; m < 2; ++m)
#pragma unroll
    for (int n = 0; n < 4; ++n)
#pragma unroll
      for (int i = 0; i < 4; ++i)
        C[(size_t)(m0 + w * 32 + m * 16 + lg * 4 + i) * 1152 + n0 + n * 16 + lr] =
            f2bf(acc[m][n][i]);
}

// ---------- gemm2 (BK=64 dual-panel) with fused V transpose+permute epilogue ----------
__global__ __launch_bounds__(256) void gemm_kv(const unsigned short* __restrict__ A,
                                               const unsigned short* __restrict__ Bt,
                                               unsigned short* __restrict__ kvK,
                                               unsigned short* __restrict__ vt) {
  __shared__ unsigned short As[2][128 * 32];
  __shared__ unsigned short Bs[2][128 * 32];
  int m0 = blockIdx.x * 128, n0 = blockIdx.y * 128;
  int tid = threadIdx.x, w = tid >> 6, l = tid & 63;
  int lr = l & 15, lg = l >> 4;
  int wr = w >> 1, wc = w & 1;
  f32x4 acc[4][4] = {};

  for (int k0 = 0; k0 < 128; k0 += 64) {
    __syncthreads();
#pragma unroll
    for (int it = 0; it < 4; ++it) {
      int s = w * 4 + it;            // 16 slots each: panel p (of 2), chunk c (of 8)
      int p = s >> 3, c = s & 7;
      int row = c * 16 + (l >> 2), col = (l & 3) * 8;
      gload_lds16(&A[(size_t)(m0 + row) * 1152 + k0 + p * 32 + col], &As[p][c * 512 + l * 8]);
      gload_lds16(&Bt[(size_t)(n0 + row) * 128 + k0 + p * 32 + col], &Bs[p][c * 512 + l * 8]);
    }
    __syncthreads();
#pragma unroll
    for (int p = 0; p < 2; ++p) {
      bf16x8 af[4], bfr[4];
#pragma unroll
      for (int m = 0; m < 4; ++m)
        af[m] = *(const bf16x8*)&As[p][(wr * 64 + m * 16 + lr) * 32 + lg * 8];
#pragma unroll
      for (int n = 0; n < 4; ++n)
        bfr[n] = *(const bf16x8*)&Bs[p][(wc * 64 + n * 16 + lr) * 32 + lg * 8];
      __builtin_amdgcn_s_setprio(1);
#pragma unroll
      for (int m = 0; m < 4; ++m)
#pragma unroll
        for (int n = 0; n < 4; ++n)
          acc[m][n] = __builtin_amdgcn_mfma_f32_16x16x32_bf16(af[m], bfr[n], acc[m][n], 0, 0, 0);
      __builtin_amdgcn_s_setprio(0);
    }
  }

  if (blockIdx.y < 8) {  // K half
#pragma unroll
    for (int m = 0; m < 4; ++m)
#pragma unroll
      for (int n = 0; n < 4; ++n)
#pragma unroll
        for (int i = 0; i < 4; ++i)
          kvK[(size_t)(m0 + wr * 64 + m * 16 + lg * 4 + i) * 2048 + n0 + wc * 64 + n * 16 + lr] =
              f2bf(acc[m][n][i]);
  } else {  // V half: transposed + pv_perm'd
#pragma unroll
    for (int m = 0; m < 4; ++m)
#pragma unroll
      for (int n = 0; n < 4; ++n) {
        int vc = n0 - 1024 + wc * 64 + n * 16 + lr;
        int hh = vc >> 6, dd = vc & 63;
        int row0 = m0 + wr * 64 + m * 16 + lg * 4;
        int bb = row0 >> 11, t0 = row0 & 2047;
        size_t vrow = (size_t)((bb * 16 + hh) * 64 + dd);
        int slot = (t0 >> 6) * 64 + pv_perm(t0 & 63);
        ushort4 o;
        o.x = f2bf(acc[m][n][0]); o.y = f2bf(acc[m][n][1]);
        o.z = f2bf(acc[m][n][2]); o.w = f2bf(acc[m][n][3]);
        *(ushort4*)&vt[vrow * 2048 + slot] = o;
      }
  }
}

// ---------- flash attention: KVBLK=128, single-buffer LDS, 3 blocks/CU ----------
// grid (bh=32, y=32), band = 31 - y (heaviest first; 1024 blocks). 4 warps;
// warp w owns rows band*64 + w*16 + lr. NT = band/2 + 1.
#define KSTR 72    // Ks row stride (64 d + 8 pad)
#define VSTR 136   // Vs row stride (128 keys + 8 pad)
__global__ __launch_bounds__(256, 3) void attn_kernel(const unsigned short* __restrict__ qg,
                                                      const unsigned short* __restrict__ kvg,
                                                      const unsigned short* __restrict__ vtg,
                                                      const float* __restrict__ biasg,
                                                      const int* __restrict__ tileokg,
                                                      float* __restrict__ outg) {
  const int bh = blockIdx.x, band = 31 - blockIdx.y;
  const int b = bh >> 4, h = bh & 15;
  const int tid = threadIdx.x, w = tid >> 6, l = tid & 63;
  const int lr = l & 15, lg = l >> 4;

  __shared__ unsigned short Ks[128 * KSTR];  // [key][d]
  __shared__ unsigned short Vs[64 * VSTR];   // [d][permuted key]

  const float QSCALE = 0.125f * 1.44269504089f;  // 1/sqrt(dh) * log2(e)

  const int NT = (band >> 1) + 1;                  // 128-key tiles for this band
  const int qrow0 = band * 64 + w * 16;
  const int dlim = (band & 1) * 64 + w * 16 + lr;  // causal limit within diag tile

  // Q fragments
  bf16x8 qf[2];
#pragma unroll
  for (int ks = 0; ks < 2; ++ks) {
    bf16x8 raw = *(const bf16x8*)&qg[(size_t)(b * 2048 + qrow0 + lr) * 1152 + h * 64 + ks * 32 + lg * 8];
#pragma unroll
    for (int j = 0; j < 8; ++j)
      raw[j] = (short)f2bf(bf2f((unsigned short)raw[j]) * QSCALE);
    qf[ks] = raw;
  }

  f32x4 acc[4] = {};
  float m_i = -1e30f, l_part = 0.f;

  // prologue: stage tile 0
  bf16x8 kreg[4], vreg[4];
#pragma unroll
  for (int it = 0; it < 4; ++it) {
    int slot = it * 256 + tid;
    int krow = slot >> 3, kc8 = (slot & 7) * 8;      // K: 128 rows x 8 chunks
    int vrow = slot >> 4, vc16 = (slot & 15) * 8;    // V: 64 rows x 16 chunks
    kreg[it] = *(const bf16x8*)&kvg[(size_t)(b * 2048 + krow) * 2048 + h * 64 + kc8];
    vreg[it] = *(const bf16x8*)&vtg[((size_t)(bh * 64 + vrow)) * 2048 + vc16];
  }
#pragma unroll
  for (int it = 0; it < 4; ++it) {
    int slot = it * 256 + tid;
    int krow = slot >> 3, kc8 = (slot & 7) * 8;
    int vrow = slot >> 4, vc16 = (slot & 15) * 8;
    *(bf16x8*)&Ks[krow * KSTR + kc8] = kreg[it];
    *(bf16x8*)&Vs[vrow * VSTR + vc16] = vreg[it];
  }
  __syncthreads();

  for (int kt = 0; kt < NT; ++kt) {
    // T14 async-stage: issue next tile's global loads now; LDS write after post-PV barrier
    if (kt + 1 < NT) {
#pragma unroll
      for (int it = 0; it < 4; ++it) {
        int slot = it * 256 + tid;
        int krow = slot >> 3, kc8 = (slot & 7) * 8;
        int vrow = slot >> 4, vc16 = (slot & 15) * 8;
        kreg[it] = *(const bf16x8*)&kvg[(size_t)(b * 2048 + (kt + 1) * 128 + krow) * 2048 + h * 64 + kc8];
        vreg[it] = *(const bf16x8*)&vtg[((size_t)(bh * 64 + vrow)) * 2048 + (kt + 1) * 128 + vc16];
      }
    }

    const bool diag = (kt == NT - 1);

    // S^T = K Q^T: 8 n-frags x 2 ks
    f32x4 s[8];
    __builtin_amdgcn_s_setprio(1);
#pragma unroll
    for (int n = 0; n < 8; ++n) {
      bf16x8 kf0 = *(const bf16x8*)&Ks[(n * 16 + lr) * KSTR + lg * 8];
      bf16x8 kf1 = *(const bf16x8*)&Ks[(n * 16 + lr) * KSTR + 32 + lg * 8];
      f32x4 z = {};
      z = __builtin_amdgcn_mfma_f32_16x16x32_bf16(kf0, qf[0], z, 0, 0, 0);
      z = __builtin_amdgcn_mfma_f32_16x16x32_bf16(kf1, qf[1], z, 0, 0, 0);
      s[n] = z;
    }
    __builtin_amdgcn_s_setprio(0);

    const int tok = tileokg[b * 32 + 2 * kt] & tileokg[b * 32 + 2 * kt + 1];
    float mx = -1e30f;
    if (tok) {
      if (diag) {
#pragma unroll
        for (int n = 0; n < 8; ++n)
#pragma unroll
          for (int i = 0; i < 4; ++i) {
            float v = (n * 16 + lg * 4 + i <= dlim) ? s[n][i] : -1e30f;
            s[n][i] = v;
            mx = fmaxf(mx, v);
          }
      } else {
#pragma unroll
        for (int n = 0; n < 8; ++n)
#pragma unroll
          for (int i = 0; i < 4; ++i)
            mx = fmaxf(mx, s[n][i]);
      }
    } else {  // rare general-mask path
#pragma unroll
      for (int n = 0; n < 8; ++n)
#pragma unroll
        for (int i = 0; i < 4; ++i) {
          int keyl = n * 16 + lg * 4 + i;
          float v = s[n][i] + biasg[b * 2048 + kt * 128 + keyl];
          if (diag) v = (keyl <= dlim) ? v : -1e30f;
          s[n][i] = v;
          mx = fmaxf(mx, v);
        }
    }
    mx = fmaxf(mx, __shfl_xor(mx, 16, 64));
    mx = fmaxf(mx, __shfl_xor(mx, 32, 64));

    // T13 defer-rescale (THR=8 in log2 domain)
    if (__any(mx - m_i > 8.0f)) {
      float mn = fmaxf(m_i, mx);
      float sc = fexp2(m_i - mn);
      m_i = mn;
      l_part *= sc;
      float scb[4];
#pragma unroll
      for (int i = 0; i < 4; ++i) scb[i] = __shfl(sc, lg * 4 + i, 64);
#pragma unroll
      for (int dt = 0; dt < 4; ++dt)
#pragma unroll
        for (int i = 0; i < 4; ++i) acc[dt][i] *= scb[i];
    }

    float rs = 0.f;
#pragma unroll
    for (int n = 0; n < 8; ++n)
#pragma unroll
      for (int i = 0; i < 4; ++i) {
        float e = fexp2(s[n][i] - m_i);
        s[n][i] = e;
        rs += e;
      }
    l_part += rs;

    // P -> PV A-fragments in registers (V pre-permuted by pv_perm per 64-sub-tile)
    unsigned pk[8][2];
#pragma unroll
    for (int n = 0; n < 8; ++n) {
      asm("v_cvt_pk_bf16_f32 %0, %1, %2" : "=v"(pk[n][0]) : "v"(s[n][0]), "v"(s[n][1]));
      asm("v_cvt_pk_bf16_f32 %0, %1, %2" : "=v"(pk[n][1]) : "v"(s[n][2]), "v"(s[n][3]));
    }
    bf16x8 paf[4];
#pragma unroll
    for (int ks = 0; ks < 4; ++ks) {
      u32x4 uv;
      uv[0] = pk[2 * ks][0];
      uv[1] = pk[2 * ks][1];
      uv[2] = pk[2 * ks + 1][0];
      uv[3] = pk[2 * ks + 1][1];
      paf[ks] = __builtin_bit_cast(bf16x8, uv);
    }

    // O += P V: 4 ks x 4 dt
    __builtin_amdgcn_s_setprio(1);
#pragma unroll
    for (int ks = 0; ks < 4; ++ks)
#pragma unroll
      for (int dt = 0; dt < 4; ++dt) {
        bf16x8 vf = *(const bf16x8*)&Vs[(dt * 16 + lr) * VSTR + ks * 32 + lg * 8];
        acc[dt] = __builtin_amdgcn_mfma_f32_16x16x32_bf16(paf[ks], vf, acc[dt], 0, 0, 0);
      }
    __builtin_amdgcn_s_setprio(0);

    // single-buffer swap: all reads done -> overwrite -> writes visible
    if (kt + 1 < NT) {
      __syncthreads();
#pragma unroll
      for (int it = 0; it < 4; ++it) {
        int slot = it * 256 + tid;
        int krow = slot >> 3, kc8 = (slot & 7) * 8;
        int vrow = slot >> 4, vc16 = (slot & 15) * 8;
        *(bf16x8*)&Ks[krow * KSTR + kc8] = kreg[it];
        *(bf16x8*)&Vs[vrow * VSTR + vc16] = vreg[it];
      }
      __syncthreads();
    }
  }

  // epilogue: finish l reduction, normalize, store
  float lt = l_part;
  lt += __shfl_xor(lt, 16, 64);
  lt += __shfl_xor(lt, 32, 64);
  float inv = 1.f / lt;
  float invb[4];
#pragma unroll
  for (int i = 0; i < 4; ++i) invb[i] = __shfl(inv, lg * 4 + i, 64);
#pragma unroll
  for (int dt = 0; dt < 4; ++dt)
#pragma unroll
    for (int i = 0; i < 4; ++i)
      outg[(size_t)(b * 2048 + qrow0 + lg * 4 + i) * 1024 + h * 64 + dt * 16 + lr] =
          acc[dt][i] * invb[i];
}

// ---------- launch ----------
extern "C" void kernel_launch(void* const* d_in, const int* in_sizes, int n_in,
                              void* d_out, int out_size, void* d_ws, size_t ws_size,
                              hipStream_t stream) {
  const float* x    = (const float*)d_in[0];
  const int*   mask = (const int*)d_in[1];
  const float* w_q  = (const float*)d_in[2];
  const float* w_d  = (const float*)d_in[3];
  const float* w_k  = (const float*)d_in[4];
  const float* w_v  = (const float*)d_in[5];
  float* out = (float*)d_out;

  char* ws = (char*)d_ws;
  size_t off = 0;
  auto alloc = [&](size_t elems) {
    unsigned short* p = (unsigned short*)(ws + off);
    off += ((elems * 2 + 255) & ~(size_t)255);
    return p;
  };
  unsigned short* x_bf = alloc(4194304);      // [4096][1024]
  unsigned short* wqdt = alloc(1152 * 1024);  // [1152][1024]
  unsigned short* wkvt = alloc(2048 * 128);   // [2048][128]
  unsigned short* qlat = alloc(4096 * 1152);  // [4096][1152]: q | latent
  unsigned short* kv   = alloc(4096 * 2048);  // [4096][2048]: K in cols 0..1023
  unsigned short* vt   = alloc(4194304);      // [32][64][2048], pv_perm'd
  float* bias = (float*)alloc(8192);          // 4096 floats
  int* tileok = (int*)alloc(128);             // 64 ints

  prep_kernel<<<2448, 256, 0, stream>>>(x, mask, w_q, w_d, w_k, w_v, x_bf, wqdt, wkvt, bias, tileok);

  gemm_q<<<dim3(32, 18), 256, 0, stream>>>(x_bf, wqdt, qlat);
  gemm_kv<<<dim3(32, 16), 256, 0, stream>>>(qlat + 1024, wkvt, kv, vt);

  attn_kernel<<<dim3(32, 32), 256, 0, stream>>>(qlat, kv, vt, bias, tileok, out);
}